// Round 17
// baseline (413.025 us; speedup 1.0000x reference)
//
#include <hip/hip_runtime.h>

#define NN 100000
#define NE 1600000
#define NG 256
#define NB 391      // ceil(NN/256)
#define NBH 1024    // histogram/scatter blocks
#define CHUNK 1563  // ceil(NE/NBH)
#define NBINS 1024  // buckets: col>>7 -> 0..781 used
#define NBUCK 782   // ceil(NN/128)

typedef __attribute__((ext_vector_type(8))) short short8v;
typedef __attribute__((ext_vector_type(4))) short short4v;
typedef __attribute__((ext_vector_type(4))) float float4v;

__device__ __forceinline__ unsigned short f2bf(float f) {
    unsigned u = __float_as_uint(f);
    return (unsigned short)((u + 0x7FFFu + ((u >> 16) & 1u)) >> 16);  // RNE
}
__device__ __forceinline__ float bf2f(unsigned short s) {
    return __uint_as_float(((unsigned)s) << 16);
}

// ---------------- bucket partition (atomic-free, LDS histograms) ----------
__global__ __launch_bounds__(256) void hist_kernel(
    const int* __restrict__ col, unsigned* __restrict__ ghist) {
    __shared__ unsigned h[NBINS];
    int b = blockIdx.x;
    for (int i = threadIdx.x; i < NBINS; i += 256) h[i] = 0;
    __syncthreads();
    int e0 = b * CHUNK;
    int e1 = e0 + CHUNK; if (e1 > NE) e1 = NE;
    for (int e = e0 + threadIdx.x; e < e1; e += 256)
        atomicAdd(&h[col[e] >> 7], 1u);
    __syncthreads();
    for (int i = threadIdx.x; i < NBINS; i += 256)
        ghist[(size_t)b * NBINS + i] = h[i];
}

__global__ __launch_bounds__(1024) void scanB_kernel(
    const unsigned* __restrict__ ghist, unsigned* __restrict__ goff,
    unsigned* __restrict__ total) {
    __shared__ unsigned a[NBH], bb[NBH];
    int bin = blockIdx.x, t = threadIdx.x;
    unsigned v = ghist[(size_t)t * NBINS + bin];
    a[t] = v;
    __syncthreads();
    unsigned* src = a; unsigned* dst = bb;
    for (int off = 1; off < NBH; off <<= 1) {
        unsigned x = src[t];
        if (t >= off) x += src[t - off];
        dst[t] = x;
        __syncthreads();
        unsigned* tmp = src; src = dst; dst = tmp;
    }
    goff[(size_t)t * NBINS + bin] = src[t] - v;  // exclusive
    if (t == NBH - 1) total[bin] = src[t];
}

__global__ __launch_bounds__(1024) void scanC_kernel(
    const unsigned* __restrict__ total, unsigned* __restrict__ binbase) {
    __shared__ unsigned a[NBINS], bb[NBINS];
    int t = threadIdx.x;
    unsigned v = total[t];
    a[t] = v;
    __syncthreads();
    unsigned* src = a; unsigned* dst = bb;
    for (int off = 1; off < NBINS; off <<= 1) {
        unsigned x = src[t];
        if (t >= off) x += src[t - off];
        dst[t] = x;
        __syncthreads();
        unsigned* tmp = src; src = dst; dst = tmp;
    }
    binbase[t] = src[t] - v;
    if (t == NBINS - 1) binbase[NBINS] = src[t];
}

// scatter into bucket order; edge features converted to packed bf16x4 (8B)
__global__ __launch_bounds__(256) void scatterD_kernel(
    const int* __restrict__ row, const int* __restrict__ col,
    const float* __restrict__ ea,
    const unsigned* __restrict__ goff, const unsigned* __restrict__ binbase,
    int2* __restrict__ rcT, unsigned short* __restrict__ eabfT) {
    __shared__ unsigned cur[NBINS];
    int b = blockIdx.x;
    for (int i = threadIdx.x; i < NBINS; i += 256) cur[i] = 0;
    __syncthreads();
    int e0 = b * CHUNK;
    int e1 = e0 + CHUNK; if (e1 > NE) e1 = NE;
    const unsigned* grow = goff + (size_t)b * NBINS;
    for (int e = e0 + threadIdx.x; e < e1; e += 256) {
        int c = col[e];
        int bin = c >> 7;
        unsigned l = atomicAdd(&cur[bin], 1u);  // LDS atomic
        unsigned slot = binbase[bin] + grow[bin] + l;
        rcT[slot] = make_int2(row[e], c);
        short4v ov;
        ov[0] = (short)f2bf(ea[(size_t)e * 3 + 0]);
        ov[1] = (short)f2bf(ea[(size_t)e * 3 + 1]);
        ov[2] = (short)f2bf(ea[(size_t)e * 3 + 2]);
        ov[3] = 0;
        *(short4v*)(eabfT + (size_t)slot * 4) = ov;
    }
}

// second-level sort: block per bucket -> full node-sorted CSR + start[]
__global__ __launch_bounds__(256) void bucketsort_kernel(
    const int2* __restrict__ rcT, const unsigned short* __restrict__ eabfT,
    const unsigned* __restrict__ binbase,
    int2* __restrict__ rc, unsigned short* __restrict__ eabf,
    unsigned* __restrict__ start)
{
    __shared__ unsigned lcnt[128], sa[128], sb[128], lcur[128];
    int bin = blockIdx.x, tid = threadIdx.x;
    if (tid < 128) lcnt[tid] = 0;
    __syncthreads();
    unsigned beg = binbase[bin], end = binbase[bin + 1];
    for (unsigned k = beg + tid; k < end; k += 256)
        atomicAdd(&lcnt[rcT[k].y & 127], 1u);
    __syncthreads();
    if (tid < 128) sa[tid] = lcnt[tid];
    __syncthreads();
    unsigned* src = sa; unsigned* dst = sb;
    for (int off = 1; off < 128; off <<= 1) {
        if (tid < 128) {
            unsigned v = src[tid];
            if (tid >= off) v += src[tid - off];
            dst[tid] = v;
        }
        __syncthreads();
        unsigned* t2 = src; src = dst; dst = t2;
    }
    if (tid < 128) {
        unsigned excl = src[tid] - lcnt[tid];
        lcur[tid] = excl;
        int n = (bin << 7) + tid;
        if (n < NN) {
            start[n] = beg + excl;
            if (n == NN - 1) start[NN] = beg + excl + lcnt[tid];
        }
    }
    __syncthreads();
    for (unsigned k = beg + tid; k < end; k += 256) {
        int2 p = rcT[k];
        unsigned l = atomicAdd(&lcur[p.y & 127], 1u);
        unsigned slot = beg + l;
        rc[slot] = p;
        *(short4v*)(eabf + (size_t)slot * 4) =
            *(const short4v*)(eabfT + (size_t)k * 4);
    }
}

// batch is sorted: graph boundaries by step detection. No atomics.
__global__ __launch_bounds__(256) void gbound_kernel(
    const int* __restrict__ batch, int* __restrict__ gstart) {
    int n = blockIdx.x * 256 + threadIdx.x;
    if (n >= NN) return;
    int b = batch[n];
    int bp = (n == 0) ? -1 : batch[n - 1];
    for (int g = bp + 1; g <= b; ++g) gstart[g] = n;
    if (n == NN - 1) {
        for (int g = b + 1; g <= NG; ++g) gstart[g] = NN;
    }
}

// x -> bf16 feature rows (8 shorts: x0..x6, pad0)
__global__ __launch_bounds__(256) void x2bf_kernel(
    const float* __restrict__ x, unsigned short* __restrict__ xbf) {
    int n = blockIdx.x * 256 + threadIdx.x;
    if (n >= NN) return;
    short8v v;
    #pragma unroll
    for (int i = 0; i < 7; ++i) v[i] = (short)f2bf(x[(size_t)n * 7 + i]);
    v[7] = 0;
    *(short8v*)(xbf + (size_t)n * 8) = v;
}

// ---------------- weight prep ----------------
// ewf k-mapping (A layout): k0..6 = xr, k8..14 = xc, k16..18 = ea, else 0.
__global__ __launch_bounds__(256) void prep_kernel(
    const float* __restrict__ eW1, const float* __restrict__ eb1, const float* __restrict__ eW2,
    const float* __restrict__ nW1, const float* __restrict__ nb1, const float* __restrict__ nW2,
    short* __restrict__ ewf, float* __restrict__ w2f, float* __restrict__ b1f,
    float* __restrict__ nwt)
{
    int t = blockIdx.x * 256 + threadIdx.x;
    const int EWF = 2 * 4096;      // 8192 shorts
    const int W2F = 2 * 1536;      // 3072 floats
    const int B1F = 2 * 512;       // 1024 floats
    const int NWT = 2 * 128 * 28;  // 7168 floats
    if (t < EWF) {
        int layer = t >> 12, r = t & 4095;
        int tt = r >> 9, r2 = r & 511;
        int l = r2 >> 3, i = r2 & 7;
        int kk = ((l >> 4) << 3) + i;
        int n = tt * 16 + (l & 15);
        int orig = -1;
        if (kk < 7)                  orig = kk;        // xr
        else if (kk >= 8 && kk < 15) orig = kk - 1;    // xc
        else if (kk >= 16 && kk < 19) orig = kk - 2;   // ea
        float v = (orig >= 0) ? eW1[layer * 17 * 128 + orig * 128 + n] : 0.f;
        ewf[t] = (short)f2bf(v);
    } else if (t < EWF + W2F) {
        int q = t - EWF;
        int layer = q / 1536, r = q % 1536;
        int l = r / 24, r2 = r % 24;
        int tt = r2 / 3, c = r2 % 3;
        int k = tt * 16 + (l & 15);
        w2f[q] = eW2[layer * 384 + k * 3 + c];
    } else if (t < EWF + W2F + B1F) {
        int q = t - EWF - W2F;
        int layer = q / 512, r = q % 512;
        int l = r / 8, tt = r % 8;
        b1f[q] = eb1[layer * 128 + tt * 16 + (l & 15)];
    } else if (t < EWF + W2F + B1F + NWT) {
        int q = t - EWF - W2F - B1F;
        int l = q / (128 * 28), rest = q % (128 * 28), j = rest / 28, i = rest % 28;
        float v = 0.f;
        if (i < 18)       v = nW1[l * 18 * 128 + i * 128 + j];
        else if (i == 18) v = nb1[l * 128 + j];
        else if (i < 26)  v = nW2[l * 128 * 7 + j * 7 + (i - 19)];
        nwt[q] = v;
    }
}

// ---------------- edge MLP via MFMA bf16, bf16 feature cache ----------------
// Per lane: ONE vector load builds the A-frag slice (xbf row / xbf col / eabf).
__global__ __launch_bounds__(256) void edge_kernel(
    const unsigned short* __restrict__ xbf, unsigned short* eabf,
    const int2* __restrict__ rc,
    const short* __restrict__ ewf, const float* __restrict__ w2f,
    const float* __restrict__ b1f, const float* __restrict__ b2)
{
    int lane = threadIdx.x & 63;
    int l15 = lane & 15, lg = lane >> 4;
    int wid = (blockIdx.x * 256 + threadIdx.x) >> 6;
    int nwaves = gridDim.x * 4;

    short8v B1[8];
    #pragma unroll
    for (int t = 0; t < 8; ++t)
        B1[t] = *(const short8v*)(ewf + (t * 64 + lane) * 8);
    float w2a[8], w2b[8], w2c[8], b1v[8];
    #pragma unroll
    for (int t = 0; t < 8; ++t) {
        w2a[t] = w2f[lane * 24 + t * 3 + 0];
        w2b[t] = w2f[lane * 24 + t * 3 + 1];
        w2c[t] = w2f[lane * 24 + t * 3 + 2];
        b1v[t] = b1f[lane * 8 + t];
    }
    float bb0 = b2[0], bb1 = b2[1], bb2 = b2[2];

    const int NT = NE / 16;    // 100000 tiles
    for (int tile = wid; tile < NT; tile += nwaves) {
        int s = tile * 16 + l15;
        int2 p = rc[s];

        short8v A = {0, 0, 0, 0, 0, 0, 0, 0};
        if (lg == 0) {
            A = *(const short8v*)(xbf + (size_t)p.x * 8);
        } else if (lg == 1) {
            A = *(const short8v*)(xbf + (size_t)p.y * 8);
        } else if (lg == 2) {
            short4v e4 = *(const short4v*)(eabf + (size_t)s * 4);
            A[0] = e4[0]; A[1] = e4[1]; A[2] = e4[2];
        }

        float4v Z = {0.f, 0.f, 0.f, 0.f};
        float4v C[8];
        #pragma unroll
        for (int t = 0; t < 8; ++t)
            C[t] = __builtin_amdgcn_mfma_f32_16x16x32_bf16(A, B1[t], Z, 0, 0, 0);

        float p00 = 0.f, p01 = 0.f, p02 = 0.f;
        float p10 = 0.f, p11 = 0.f, p12 = 0.f;
        float p20 = 0.f, p21 = 0.f, p22 = 0.f;
        float p30 = 0.f, p31 = 0.f, p32 = 0.f;
        #pragma unroll
        for (int t = 0; t < 8; ++t) {
            float h0 = fmaxf(C[t][0] + b1v[t], 0.f);
            float h1 = fmaxf(C[t][1] + b1v[t], 0.f);
            float h2 = fmaxf(C[t][2] + b1v[t], 0.f);
            float h3 = fmaxf(C[t][3] + b1v[t], 0.f);
            p00 += h0 * w2a[t]; p01 += h0 * w2b[t]; p02 += h0 * w2c[t];
            p10 += h1 * w2a[t]; p11 += h1 * w2b[t]; p12 += h1 * w2c[t];
            p20 += h2 * w2a[t]; p21 += h2 * w2b[t]; p22 += h2 * w2c[t];
            p30 += h3 * w2a[t]; p31 += h3 * w2b[t]; p32 += h3 * w2c[t];
        }
        #pragma unroll
        for (int m = 1; m < 16; m <<= 1) {
            p00 += __shfl_xor(p00, m, 16); p01 += __shfl_xor(p01, m, 16); p02 += __shfl_xor(p02, m, 16);
            p10 += __shfl_xor(p10, m, 16); p11 += __shfl_xor(p11, m, 16); p12 += __shfl_xor(p12, m, 16);
            p20 += __shfl_xor(p20, m, 16); p21 += __shfl_xor(p21, m, 16); p22 += __shfl_xor(p22, m, 16);
            p30 += __shfl_xor(p30, m, 16); p31 += __shfl_xor(p31, m, 16); p32 += __shfl_xor(p32, m, 16);
        }
        if (l15 < 4) {
            float o0 = (l15 == 0) ? p00 : (l15 == 1) ? p10 : (l15 == 2) ? p20 : p30;
            float o1 = (l15 == 0) ? p01 : (l15 == 1) ? p11 : (l15 == 2) ? p21 : p31;
            float o2 = (l15 == 0) ? p02 : (l15 == 1) ? p12 : (l15 == 2) ? p22 : p32;
            short4v ov;
            ov[0] = (short)f2bf(o0 + bb0);
            ov[1] = (short)f2bf(o1 + bb1);
            ov[2] = (short)f2bf(o2 + bb2);
            ov[3] = 0;
            size_t eo = (size_t)(tile * 16 + lg * 4 + l15);
            *(short4v*)(eabf + eo * 4) = ov;
        }
    }
}

// ---------------- segment reduce: 16 lanes per node ----------------
__global__ __launch_bounds__(256) void reduce_kernel(
    const unsigned short* __restrict__ eabf, const unsigned* __restrict__ start,
    const float* __restrict__ u, const int* __restrict__ batch,
    float* __restrict__ nred)
{
    int gid = blockIdx.x * 256 + threadIdx.x;
    int n = gid >> 4, sub = gid & 15;
    if (n >= NN) return;
    unsigned sbeg = start[n], send = start[n + 1];

    float s0 = 0.f, s1 = 0.f, s2 = 0.f;
    float m0 = -__builtin_inff(), m1 = -__builtin_inff(), m2 = -__builtin_inff();
    for (unsigned k = sbeg + sub; k < send; k += 16) {
        short4v w = *(const short4v*)(eabf + (size_t)k * 4);
        float v0 = bf2f((unsigned short)w[0]);
        float v1 = bf2f((unsigned short)w[1]);
        float v2 = bf2f((unsigned short)w[2]);
        s0 += v0; s1 += v1; s2 += v2;
        m0 = fmaxf(m0, v0); m1 = fmaxf(m1, v1); m2 = fmaxf(m2, v2);
    }
    #pragma unroll
    for (int msk = 1; msk < 16; msk <<= 1) {
        s0 += __shfl_xor(s0, msk, 16);
        s1 += __shfl_xor(s1, msk, 16);
        s2 += __shfl_xor(s2, msk, 16);
        m0 = fmaxf(m0, __shfl_xor(m0, msk, 16));
        m1 = fmaxf(m1, __shfl_xor(m1, msk, 16));
        m2 = fmaxf(m2, __shfl_xor(m2, msk, 16));
    }
    if (sub == 0) {
        float deg = (float)(send - sbeg);
        if (send == sbeg) { m0 = 0.f; m1 = 0.f; m2 = 0.f; }
        float inv = 1.f / fmaxf(deg, 1.f);
        int b = batch[n];
        float* o = nred + (size_t)n * 12;
        o[0] = s0; o[1] = s1; o[2] = s2;
        o[3] = m0; o[4] = m1; o[5] = m2;
        o[6] = s0 * inv; o[7] = s1 * inv; o[8] = s2 * inv;
        o[9] = u[b * 2 + 0]; o[10] = u[b * 2 + 1];
    }
}

// ---------------- node MLP: wave-per-node, weight-stationary ----------------
#define NMLP_BLOCKS 1024
#define NMLP_WAVES (NMLP_BLOCKS * 4)
__global__ __launch_bounds__(256, 4) void nodemlp_kernel(
    const float* x_in, const float* __restrict__ nred,
    const float* __restrict__ wt, const float* __restrict__ b2,
    float* x_out, unsigned short* __restrict__ xbf_out)
{
    int lane = threadIdx.x & 63;
    int wid = (blockIdx.x * 256 + threadIdx.x) >> 6;

    const float* ra = wt + lane * 28;
    const float* rb = wt + (lane + 64) * 28;
    float a0 = ra[0], a1 = ra[1], a2 = ra[2], a3 = ra[3], a4 = ra[4], a5 = ra[5],
          a6 = ra[6], a7 = ra[7], a8 = ra[8], a9 = ra[9], a10 = ra[10], a11 = ra[11],
          a12 = ra[12], a13 = ra[13], a14 = ra[14], a15 = ra[15], a16 = ra[16], a17 = ra[17],
          ab = ra[18], p0 = ra[19], p1 = ra[20], p2 = ra[21], p3 = ra[22], p4 = ra[23],
          p5 = ra[24], p6 = ra[25];
    float b0 = rb[0], b1 = rb[1], b2_ = rb[2], b3 = rb[3], b4 = rb[4], b5 = rb[5],
          b6 = rb[6], b7 = rb[7], b8 = rb[8], b9 = rb[9], b10 = rb[10], b11 = rb[11],
          b12 = rb[12], b13 = rb[13], b14 = rb[14], b15 = rb[15], b16 = rb[16], b17 = rb[17],
          bb = rb[18], q0 = rb[19], q1 = rb[20], q2 = rb[21], q3 = rb[22], q4 = rb[23],
          q5 = rb[24], q6 = rb[25];

    asm volatile("" : "+v"(a0), "+v"(a1), "+v"(a2), "+v"(a3), "+v"(a4), "+v"(a5),
                      "+v"(a6), "+v"(a7), "+v"(a8), "+v"(a9), "+v"(a10), "+v"(a11),
                      "+v"(a12), "+v"(a13), "+v"(a14), "+v"(a15), "+v"(a16), "+v"(a17),
                      "+v"(ab), "+v"(p0), "+v"(p1), "+v"(p2), "+v"(p3), "+v"(p4),
                      "+v"(p5), "+v"(p6));
    asm volatile("" : "+v"(b0), "+v"(b1), "+v"(b2_), "+v"(b3), "+v"(b4), "+v"(b5),
                      "+v"(b6), "+v"(b7), "+v"(b8), "+v"(b9), "+v"(b10), "+v"(b11),
                      "+v"(b12), "+v"(b13), "+v"(b14), "+v"(b15), "+v"(b16), "+v"(b17),
                      "+v"(bb), "+v"(q0), "+v"(q1), "+v"(q2), "+v"(q3), "+v"(q4),
                      "+v"(q5), "+v"(q6));

    float B0 = b2[0], B1 = b2[1], B2 = b2[2], B3 = b2[3], B4 = b2[4], B5 = b2[5], B6 = b2[6];

    const int nper = (NN + NMLP_WAVES - 1) / NMLP_WAVES;   // 25
    int n0 = wid * nper;
    int n1 = n0 + nper; if (n1 > NN) n1 = NN;

    #pragma unroll 2
    for (int n = n0; n < n1; ++n) {
        int nu = __builtin_amdgcn_readfirstlane(n);
        const float* xp = x_in + (size_t)nu * 7;
        const float* rp = nred + (size_t)nu * 12;
        float i0 = xp[0], i1 = xp[1], i2 = xp[2], i3 = xp[3], i4 = xp[4], i5 = xp[5], i6 = xp[6];
        float s0 = rp[0], s1 = rp[1], s2 = rp[2];
        float m0 = rp[3], m1 = rp[4], m2 = rp[5];
        float e0 = rp[6], e1 = rp[7], e2 = rp[8];
        float u0 = rp[9], u1 = rp[10];

        float ha = ab, hb = bb;
        ha += i0 * a0;  hb += i0 * b0;
        ha += i1 * a1;  hb += i1 * b1;
        ha += i2 * a2;  hb += i2 * b2_;
        ha += i3 * a3;  hb += i3 * b3;
        ha += i4 * a4;  hb += i4 * b4;
        ha += i5 * a5;  hb += i5 * b5;
        ha += i6 * a6;  hb += i6 * b6;
        ha += s0 * a7;  hb += s0 * b7;
        ha += s1 * a8;  hb += s1 * b8;
        ha += s2 * a9;  hb += s2 * b9;
        ha += m0 * a10; hb += m0 * b10;
        ha += m1 * a11; hb += m1 * b11;
        ha += m2 * a12; hb += m2 * b12;
        ha += e0 * a13; hb += e0 * b13;
        ha += e1 * a14; hb += e1 * b14;
        ha += e2 * a15; hb += e2 * b15;
        ha += u0 * a16; hb += u0 * b16;
        ha += u1 * a17; hb += u1 * b17;
        ha = fmaxf(ha, 0.f); hb = fmaxf(hb, 0.f);

        float c0 = ha * p0 + hb * q0;
        float c1 = ha * p1 + hb * q1;
        float c2 = ha * p2 + hb * q2;
        float c3 = ha * p3 + hb * q3;
        float c4 = ha * p4 + hb * q4;
        float c5 = ha * p5 + hb * q5;
        float c6 = ha * p6 + hb * q6;
        #pragma unroll
        for (int msk = 1; msk < 64; msk <<= 1) {
            c0 += __shfl_xor(c0, msk);
            c1 += __shfl_xor(c1, msk);
            c2 += __shfl_xor(c2, msk);
            c3 += __shfl_xor(c3, msk);
            c4 += __shfl_xor(c4, msk);
            c5 += __shfl_xor(c5, msk);
            c6 += __shfl_xor(c6, msk);
        }
        float o = c0 + B0;
        if (lane == 1) o = c1 + B1;
        if (lane == 2) o = c2 + B2;
        if (lane == 3) o = c3 + B3;
        if (lane == 4) o = c4 + B4;
        if (lane == 5) o = c5 + B5;
        if (lane == 6) o = c6 + B6;
        if (lane < 7) {
            x_out[(size_t)nu * 7 + lane] = o;
            xbf_out[(size_t)nu * 8 + lane] = f2bf(o);
        }
        if (lane == 7) xbf_out[(size_t)nu * 8 + 7] = 0;
    }
}

// ---------------- fused graph pool + output head (block per graph) ----------
__global__ __launch_bounds__(256) void pool_head_kernel(
    const float* __restrict__ x, const int* __restrict__ gstart,
    const float* __restrict__ u,
    const float* __restrict__ oW1, const float* __restrict__ ob1,
    const float* __restrict__ oW2, const float* __restrict__ ob2,
    const float* __restrict__ oW3, const float* __restrict__ ob3,
    const float* __restrict__ oW4, const float* __restrict__ ob4,
    float* __restrict__ out)
{
    int g = blockIdx.x, tid = threadIdx.x;
    int lane = tid & 63, wv = tid >> 6;
    int gs = gstart[g], ge = gstart[g + 1];

    float s0 = 0.f, s1 = 0.f, s2 = 0.f, s3 = 0.f, s4 = 0.f, s5 = 0.f, s6 = 0.f;
    float m0 = -__builtin_inff(), m1 = m0, m2 = m0, m3 = m0, m4 = m0, m5 = m0, m6 = m0;
    for (int n = gs + tid; n < ge; n += 256) {
        const float* xp = x + (size_t)n * 7;
        float v0 = xp[0], v1 = xp[1], v2 = xp[2], v3 = xp[3], v4 = xp[4], v5 = xp[5], v6 = xp[6];
        s0 += v0; s1 += v1; s2 += v2; s3 += v3; s4 += v4; s5 += v5; s6 += v6;
        m0 = fmaxf(m0, v0); m1 = fmaxf(m1, v1); m2 = fmaxf(m2, v2); m3 = fmaxf(m3, v3);
        m4 = fmaxf(m4, v4); m5 = fmaxf(m5, v5); m6 = fmaxf(m6, v6);
    }
    #pragma unroll
    for (int msk = 1; msk < 64; msk <<= 1) {
        s0 += __shfl_xor(s0, msk); s1 += __shfl_xor(s1, msk); s2 += __shfl_xor(s2, msk);
        s3 += __shfl_xor(s3, msk); s4 += __shfl_xor(s4, msk); s5 += __shfl_xor(s5, msk);
        s6 += __shfl_xor(s6, msk);
        m0 = fmaxf(m0, __shfl_xor(m0, msk)); m1 = fmaxf(m1, __shfl_xor(m1, msk));
        m2 = fmaxf(m2, __shfl_xor(m2, msk)); m3 = fmaxf(m3, __shfl_xor(m3, msk));
        m4 = fmaxf(m4, __shfl_xor(m4, msk)); m5 = fmaxf(m5, __shfl_xor(m5, msk));
        m6 = fmaxf(m6, __shfl_xor(m6, msk));
    }
    __shared__ float red[4][14];
    __shared__ float hin[23];
    __shared__ float ha[128];
    __shared__ float hbuf[128];
    if (lane == 0) {
        red[wv][0] = s0; red[wv][1] = s1; red[wv][2] = s2; red[wv][3] = s3;
        red[wv][4] = s4; red[wv][5] = s5; red[wv][6] = s6;
        red[wv][7] = m0; red[wv][8] = m1; red[wv][9] = m2; red[wv][10] = m3;
        red[wv][11] = m4; red[wv][12] = m5; red[wv][13] = m6;
    }
    __syncthreads();
    if (tid < 7) {
        float S = red[0][tid] + red[1][tid] + red[2][tid] + red[3][tid];
        float M = fmaxf(fmaxf(red[0][7 + tid], red[1][7 + tid]),
                        fmaxf(red[2][7 + tid], red[3][7 + tid]));
        float cntf = (float)(ge - gs);
        if (ge == gs) M = 0.f;
        hin[tid] = S;
        hin[7 + tid] = S / fmaxf(cntf, 1.f);
        hin[14 + tid] = M;
    }
    if (tid < 2) hin[21 + tid] = u[g * 2 + tid];
    __syncthreads();

    float h = 0.f;
    if (tid < 128) {
        h = ob1[tid];
        for (int i = 0; i < 23; ++i) h += hin[i] * oW1[i * 128 + tid];
        ha[tid] = fmaxf(h, 0.f);
    }
    __syncthreads();
    if (tid < 128) {
        h = ob2[tid];
        for (int i = 0; i < 128; ++i) h += ha[i] * oW2[i * 128 + tid];
        hbuf[tid] = fmaxf(h, 0.f);
    }
    __syncthreads();
    if (tid < 128) {
        h = ob3[tid];
        for (int i = 0; i < 128; ++i) h += hbuf[i] * oW3[i * 128 + tid];
        ha[tid] = fmaxf(h, 0.f) * oW4[tid];
    }
    __syncthreads();
    if (tid == 0) {
        float acc = ob4[0];
        for (int i = 0; i < 128; ++i) acc += ha[i];
        out[g] = acc;
    }
}

extern "C" void kernel_launch(void* const* d_in, const int* in_sizes, int n_in,
                              void* d_out, int out_size, void* d_ws, size_t ws_size,
                              hipStream_t stream) {
    const float* x         = (const float*)d_in[0];
    const float* edge_attr = (const float*)d_in[1];
    const float* u         = (const float*)d_in[2];
    const float* eW1 = (const float*)d_in[3];
    const float* eb1 = (const float*)d_in[4];
    const float* eW2 = (const float*)d_in[5];
    const float* eb2 = (const float*)d_in[6];
    const float* nW1 = (const float*)d_in[7];
    const float* nb1 = (const float*)d_in[8];
    const float* nW2 = (const float*)d_in[9];
    const float* nb2 = (const float*)d_in[10];
    const float* oW1 = (const float*)d_in[11];
    const float* ob1 = (const float*)d_in[12];
    const float* oW2 = (const float*)d_in[13];
    const float* ob2 = (const float*)d_in[14];
    const float* oW3 = (const float*)d_in[15];
    const float* ob3 = (const float*)d_in[16];
    const float* oW4 = (const float*)d_in[17];
    const float* ob4 = (const float*)d_in[18];
    const int* edge_index = (const int*)d_in[19];
    const int* batch      = (const int*)d_in[20];
    const int* row = edge_index;
    const int* col = edge_index + NE;

    // workspace layout (byte arithmetic; all sizes multiples of 16B)
    char* base = (char*)d_ws;
    unsigned short* eabf  = (unsigned short*)base;  base += (size_t)NE * 4 * 2;   // 12.8 MB
    unsigned short* eabfT = (unsigned short*)base;  base += (size_t)NE * 4 * 2;   // 12.8 MB
    unsigned short* xbf0  = (unsigned short*)base;  base += (size_t)NN * 8 * 2;   // 1.6 MB
    unsigned short* xbfA  = (unsigned short*)base;  base += (size_t)NN * 8 * 2;   // 1.6 MB
    float* xA   = (float*)base;                     base += (size_t)NN * 7 * 4;
    float* xB   = (float*)base;                     base += (size_t)NN * 7 * 4;
    int2* rc    = (int2*)base;                      base += (size_t)NE * 8;
    int2* rcT   = (int2*)base;                      base += (size_t)NE * 8;
    float* nred = (float*)base;                     base += (size_t)NN * 12 * 4;
    unsigned* ghist = (unsigned*)base;              base += (size_t)NBH * NBINS * 4;
    unsigned* goff  = (unsigned*)base;              base += (size_t)NBH * NBINS * 4;
    unsigned* total = (unsigned*)base;              base += NBINS * 4;
    unsigned* binbase = (unsigned*)base;            base += (NBINS + 4) * 4;
    unsigned* startv = (unsigned*)base;             base += (NN + 4) * 4;
    int* gstart = (int*)base;                       base += 260 * 4;
    float* nwt = (float*)base;                      base += 2 * 128 * 28 * 4;
    float* w2f = (float*)base;                      base += 2 * 1536 * 4;
    float* b1f = (float*)base;                      base += 2 * 512 * 4;
    short* ewf = (short*)(((uintptr_t)base + 15) & ~(uintptr_t)15);

    dim3 b256(256);
    dim3 gn(NB);                        // 391

    // ---- atomic-free two-level partition -> node-sorted CSR (bf16 feats) ----
    hist_kernel<<<NBH, b256, 0, stream>>>(col, ghist);
    gbound_kernel<<<gn, b256, 0, stream>>>(batch, gstart);
    x2bf_kernel<<<gn, b256, 0, stream>>>(x, xbf0);
    scanB_kernel<<<NBINS, 1024, 0, stream>>>(ghist, goff, total);
    scanC_kernel<<<1, 1024, 0, stream>>>(total, binbase);
    scatterD_kernel<<<NBH, b256, 0, stream>>>(row, col, edge_attr, goff, binbase, rcT, eabfT);
    bucketsort_kernel<<<NBUCK, b256, 0, stream>>>(rcT, eabfT, binbase, rc, eabf, startv);

    // weight prep
    {
        int t = 2 * 4096 + 2 * 1536 + 2 * 512 + 2 * 128 * 28;  // 19456
        prep_kernel<<<(t + 255) / 256, b256, 0, stream>>>(
            eW1, eb1, eW2, nW1, nb1, nW2, ewf, w2f, b1f, nwt);
    }

    dim3 gemf(2048);                  // edge MFMA grid (8192 waves)
    dim3 gr((NN * 16 + 255) / 256);   // 6250 blocks for reduce

    // ---- layer 0 ----
    edge_kernel<<<gemf, b256, 0, stream>>>(xbf0, eabf, rc, ewf, w2f, b1f, eb2);
    reduce_kernel<<<gr, b256, 0, stream>>>(eabf, startv, u, batch, nred);
    nodemlp_kernel<<<NMLP_BLOCKS, b256, 0, stream>>>(x, nred, nwt, nb2, xA, xbfA);

    // ---- layer 1 ----
    edge_kernel<<<gemf, b256, 0, stream>>>(xbfA, eabf, rc,
        ewf + 4096, w2f + 1536, b1f + 512, eb2 + 3);
    reduce_kernel<<<gr, b256, 0, stream>>>(eabf, startv, u, batch, nred);
    nodemlp_kernel<<<NMLP_BLOCKS, b256, 0, stream>>>(xA, nred,
        nwt + 128 * 28, nb2 + 7, xB, xbfA);

    // ---- fused pool + head ----
    pool_head_kernel<<<NG, b256, 0, stream>>>(xB, gstart, u,
        oW1, ob1, oW2, ob2, oW3, ob3, oW4, ob4, (float*)d_out);
}

// Round 18
// 394.740 us; speedup vs baseline: 1.0463x; 1.0463x over previous
//
#include <hip/hip_runtime.h>

#define NN 100000
#define NE 1600000
#define NG 256
#define NB 391      // ceil(NN/256)
#define NBH 1024    // histogram/scatter blocks
#define CHUNK 1563  // ceil(NE/NBH)
#define NBINS 1024  // buckets: col>>7 -> 0..781 used
#define NBUCK 782   // ceil(NN/128)

typedef __attribute__((ext_vector_type(8))) short short8v;
typedef __attribute__((ext_vector_type(4))) float float4v;

__device__ __forceinline__ unsigned short f2bf(float f) {
    unsigned u = __float_as_uint(f);
    return (unsigned short)((u + 0x7FFFu + ((u >> 16) & 1u)) >> 16);  // RNE
}

// ---------------- bucket partition (atomic-free, LDS histograms) ----------
__global__ __launch_bounds__(256) void hist_kernel(
    const int* __restrict__ col, unsigned* __restrict__ ghist) {
    __shared__ unsigned h[NBINS];
    int b = blockIdx.x;
    for (int i = threadIdx.x; i < NBINS; i += 256) h[i] = 0;
    __syncthreads();
    int e0 = b * CHUNK;
    int e1 = e0 + CHUNK; if (e1 > NE) e1 = NE;
    for (int e = e0 + threadIdx.x; e < e1; e += 256)
        atomicAdd(&h[col[e] >> 7], 1u);
    __syncthreads();
    for (int i = threadIdx.x; i < NBINS; i += 256)
        ghist[(size_t)b * NBINS + i] = h[i];
}

__global__ __launch_bounds__(1024) void scanB_kernel(
    const unsigned* __restrict__ ghist, unsigned* __restrict__ goff,
    unsigned* __restrict__ total) {
    __shared__ unsigned a[NBH], bb[NBH];
    int bin = blockIdx.x, t = threadIdx.x;
    unsigned v = ghist[(size_t)t * NBINS + bin];
    a[t] = v;
    __syncthreads();
    unsigned* src = a; unsigned* dst = bb;
    for (int off = 1; off < NBH; off <<= 1) {
        unsigned x = src[t];
        if (t >= off) x += src[t - off];
        dst[t] = x;
        __syncthreads();
        unsigned* tmp = src; src = dst; dst = tmp;
    }
    goff[(size_t)t * NBINS + bin] = src[t] - v;  // exclusive
    if (t == NBH - 1) total[bin] = src[t];
}

__global__ __launch_bounds__(1024) void scanC_kernel(
    const unsigned* __restrict__ total, unsigned* __restrict__ binbase) {
    __shared__ unsigned a[NBINS], bb[NBINS];
    int t = threadIdx.x;
    unsigned v = total[t];
    a[t] = v;
    __syncthreads();
    unsigned* src = a; unsigned* dst = bb;
    for (int off = 1; off < NBINS; off <<= 1) {
        unsigned x = src[t];
        if (t >= off) x += src[t - off];
        dst[t] = x;
        __syncthreads();
        unsigned* tmp = src; src = dst; dst = tmp;
    }
    binbase[t] = src[t] - v;
    if (t == NBINS - 1) binbase[NBINS] = src[t];
}

__global__ __launch_bounds__(256) void scatterD_kernel(
    const int* __restrict__ row, const int* __restrict__ col,
    const float* __restrict__ ea,
    const unsigned* __restrict__ goff, const unsigned* __restrict__ binbase,
    int2* __restrict__ rcT, float* __restrict__ eabT) {
    __shared__ unsigned cur[NBINS];
    int b = blockIdx.x;
    for (int i = threadIdx.x; i < NBINS; i += 256) cur[i] = 0;
    __syncthreads();
    int e0 = b * CHUNK;
    int e1 = e0 + CHUNK; if (e1 > NE) e1 = NE;
    const unsigned* grow = goff + (size_t)b * NBINS;
    for (int e = e0 + threadIdx.x; e < e1; e += 256) {
        int c = col[e];
        int bin = c >> 7;
        unsigned l = atomicAdd(&cur[bin], 1u);  // LDS atomic
        unsigned slot = binbase[bin] + grow[bin] + l;
        rcT[slot] = make_int2(row[e], c);
        eabT[(size_t)slot * 3 + 0] = ea[(size_t)e * 3 + 0];
        eabT[(size_t)slot * 3 + 1] = ea[(size_t)e * 3 + 1];
        eabT[(size_t)slot * 3 + 2] = ea[(size_t)e * 3 + 2];
    }
}

// second-level sort: block per bucket -> full node-sorted CSR + start[]
__global__ __launch_bounds__(256) void bucketsort_kernel(
    const int2* __restrict__ rcT, const float* __restrict__ eabT,
    const unsigned* __restrict__ binbase,
    int2* __restrict__ rc, float* __restrict__ eab, unsigned* __restrict__ start)
{
    __shared__ unsigned lcnt[128], sa[128], sb[128], lcur[128];
    int bin = blockIdx.x, tid = threadIdx.x;
    if (tid < 128) lcnt[tid] = 0;
    __syncthreads();
    unsigned beg = binbase[bin], end = binbase[bin + 1];
    for (unsigned k = beg + tid; k < end; k += 256)
        atomicAdd(&lcnt[rcT[k].y & 127], 1u);
    __syncthreads();
    if (tid < 128) sa[tid] = lcnt[tid];
    __syncthreads();
    unsigned* src = sa; unsigned* dst = sb;
    for (int off = 1; off < 128; off <<= 1) {
        if (tid < 128) {
            unsigned v = src[tid];
            if (tid >= off) v += src[tid - off];
            dst[tid] = v;
        }
        __syncthreads();
        unsigned* t2 = src; src = dst; dst = t2;
    }
    if (tid < 128) {
        unsigned excl = src[tid] - lcnt[tid];
        lcur[tid] = excl;
        int n = (bin << 7) + tid;
        if (n < NN) {
            start[n] = beg + excl;
            if (n == NN - 1) start[NN] = beg + excl + lcnt[tid];
        }
    }
    __syncthreads();
    for (unsigned k = beg + tid; k < end; k += 256) {
        int2 p = rcT[k];
        unsigned l = atomicAdd(&lcur[p.y & 127], 1u);
        unsigned slot = beg + l;
        rc[slot] = p;
        eab[(size_t)slot * 3 + 0] = eabT[(size_t)k * 3 + 0];
        eab[(size_t)slot * 3 + 1] = eabT[(size_t)k * 3 + 1];
        eab[(size_t)slot * 3 + 2] = eabT[(size_t)k * 3 + 2];
    }
}

// batch is sorted: graph boundaries by step detection. No atomics.
__global__ __launch_bounds__(256) void gbound_kernel(
    const int* __restrict__ batch, int* __restrict__ gstart) {
    int n = blockIdx.x * 256 + threadIdx.x;
    if (n >= NN) return;
    int b = batch[n];
    int bp = (n == 0) ? -1 : batch[n - 1];
    for (int g = bp + 1; g <= b; ++g) gstart[g] = n;
    if (n == NN - 1) {
        for (int g = b + 1; g <= NG; ++g) gstart[g] = NN;
    }
}

// ---------------- weight prep ----------------
__global__ __launch_bounds__(256) void prep_kernel(
    const float* __restrict__ eW1, const float* __restrict__ eb1, const float* __restrict__ eW2,
    const float* __restrict__ nW1, const float* __restrict__ nb1, const float* __restrict__ nW2,
    short* __restrict__ ewf, float* __restrict__ w2f, float* __restrict__ b1f,
    float* __restrict__ nwt)
{
    int t = blockIdx.x * 256 + threadIdx.x;
    const int EWF = 2 * 4096;      // 8192 shorts
    const int W2F = 2 * 1536;      // 3072 floats
    const int B1F = 2 * 512;       // 1024 floats
    const int NWT = 2 * 128 * 28;  // 7168 floats
    if (t < EWF) {
        int layer = t >> 12, r = t & 4095;
        int tt = r >> 9, r2 = r & 511;
        int l = r2 >> 3, i = r2 & 7;
        int kk = ((l >> 4) << 3) + i;
        int n = tt * 16 + (l & 15);
        float v = (kk < 17) ? eW1[layer * 17 * 128 + kk * 128 + n] : 0.f;
        ewf[t] = (short)f2bf(v);
    } else if (t < EWF + W2F) {
        int q = t - EWF;
        int layer = q / 1536, r = q % 1536;
        int l = r / 24, r2 = r % 24;
        int tt = r2 / 3, c = r2 % 3;
        int k = tt * 16 + (l & 15);
        w2f[q] = eW2[layer * 384 + k * 3 + c];
    } else if (t < EWF + W2F + B1F) {
        int q = t - EWF - W2F;
        int layer = q / 512, r = q % 512;
        int l = r / 8, tt = r % 8;
        b1f[q] = eb1[layer * 128 + tt * 16 + (l & 15)];
    } else if (t < EWF + W2F + B1F + NWT) {
        int q = t - EWF - W2F - B1F;
        int l = q / (128 * 28), rest = q % (128 * 28), j = rest / 28, i = rest % 28;
        float v = 0.f;
        if (i < 18)       v = nW1[l * 18 * 128 + i * 128 + j];
        else if (i == 18) v = nb1[l * 128 + j];
        else if (i < 26)  v = nW2[l * 128 * 7 + j * 7 + (i - 19)];
        nwt[q] = v;
    }
}

// ---------------- edge MLP via MFMA bf16, 2x4 accumulator groups -----------
// Same as R10/R16 proven form, but MFMAs issued in two groups of 4 with
// immediate consumption -> live accumulator block halves (32->16 AGPR).
__global__ __launch_bounds__(256) void edge_kernel(
    const float* __restrict__ x, float* eab,
    const int2* __restrict__ rc,
    const short* __restrict__ ewf, const float* __restrict__ w2f,
    const float* __restrict__ b1f, const float* __restrict__ b2)
{
    int lane = threadIdx.x & 63;
    int l15 = lane & 15, lg = lane >> 4;
    int wid = (blockIdx.x * 256 + threadIdx.x) >> 6;
    int nwaves = gridDim.x * 4;

    short8v B1[8];
    #pragma unroll
    for (int t = 0; t < 8; ++t)
        B1[t] = *(const short8v*)(ewf + (t * 64 + lane) * 8);
    float w2a[8], w2b[8], w2c[8], b1v[8];
    #pragma unroll
    for (int t = 0; t < 8; ++t) {
        w2a[t] = w2f[lane * 24 + t * 3 + 0];
        w2b[t] = w2f[lane * 24 + t * 3 + 1];
        w2c[t] = w2f[lane * 24 + t * 3 + 2];
        b1v[t] = b1f[lane * 8 + t];
    }
    float bb0 = b2[0], bb1 = b2[1], bb2 = b2[2];

    const int NT = NE / 16;    // 100000 tiles
    for (int tile = wid; tile < NT; tile += nwaves) {
        int s = tile * 16 + l15;
        int2 p = rc[s];
        const float* xr = x + (size_t)p.x * 7;
        const float* xc = x + (size_t)p.y * 7;
        const float* ep = eab + (size_t)s * 3;

        float av0 = 0.f, av1 = 0.f, av2 = 0.f, av3 = 0.f,
              av4 = 0.f, av5 = 0.f, av6 = 0.f, av7 = 0.f;
        if (lg == 0) {
            av0 = xr[0]; av1 = xr[1]; av2 = xr[2]; av3 = xr[3];
            av4 = xr[4]; av5 = xr[5]; av6 = xr[6]; av7 = xc[0];
        } else if (lg == 1) {
            av0 = xc[1]; av1 = xc[2]; av2 = xc[3]; av3 = xc[4];
            av4 = xc[5]; av5 = xc[6]; av6 = ep[0]; av7 = ep[1];
        } else if (lg == 2) {
            av0 = ep[2];
        }

        short8v A;
        A[0] = (short)f2bf(av0); A[1] = (short)f2bf(av1);
        A[2] = (short)f2bf(av2); A[3] = (short)f2bf(av3);
        A[4] = (short)f2bf(av4); A[5] = (short)f2bf(av5);
        A[6] = (short)f2bf(av6); A[7] = (short)f2bf(av7);

        float4v Z = {0.f, 0.f, 0.f, 0.f};
        float p00 = 0.f, p01 = 0.f, p02 = 0.f;
        float p10 = 0.f, p11 = 0.f, p12 = 0.f;
        float p20 = 0.f, p21 = 0.f, p22 = 0.f;
        float p30 = 0.f, p31 = 0.f, p32 = 0.f;

        #pragma unroll
        for (int g = 0; g < 2; ++g) {
            float4v C[4];
            #pragma unroll
            for (int q = 0; q < 4; ++q)
                C[q] = __builtin_amdgcn_mfma_f32_16x16x32_bf16(A, B1[g * 4 + q], Z, 0, 0, 0);
            #pragma unroll
            for (int q = 0; q < 4; ++q) {
                int t = g * 4 + q;
                float h0 = fmaxf(C[q][0] + b1v[t], 0.f);
                float h1 = fmaxf(C[q][1] + b1v[t], 0.f);
                float h2 = fmaxf(C[q][2] + b1v[t], 0.f);
                float h3 = fmaxf(C[q][3] + b1v[t], 0.f);
                p00 += h0 * w2a[t]; p01 += h0 * w2b[t]; p02 += h0 * w2c[t];
                p10 += h1 * w2a[t]; p11 += h1 * w2b[t]; p12 += h1 * w2c[t];
                p20 += h2 * w2a[t]; p21 += h2 * w2b[t]; p22 += h2 * w2c[t];
                p30 += h3 * w2a[t]; p31 += h3 * w2b[t]; p32 += h3 * w2c[t];
            }
        }
        #pragma unroll
        for (int m = 1; m < 16; m <<= 1) {
            p00 += __shfl_xor(p00, m, 16); p01 += __shfl_xor(p01, m, 16); p02 += __shfl_xor(p02, m, 16);
            p10 += __shfl_xor(p10, m, 16); p11 += __shfl_xor(p11, m, 16); p12 += __shfl_xor(p12, m, 16);
            p20 += __shfl_xor(p20, m, 16); p21 += __shfl_xor(p21, m, 16); p22 += __shfl_xor(p22, m, 16);
            p30 += __shfl_xor(p30, m, 16); p31 += __shfl_xor(p31, m, 16); p32 += __shfl_xor(p32, m, 16);
        }
        if (l15 < 4) {
            float o0 = (l15 == 0) ? p00 : (l15 == 1) ? p10 : (l15 == 2) ? p20 : p30;
            float o1 = (l15 == 0) ? p01 : (l15 == 1) ? p11 : (l15 == 2) ? p21 : p31;
            float o2 = (l15 == 0) ? p02 : (l15 == 1) ? p12 : (l15 == 2) ? p22 : p32;
            size_t off = (size_t)(tile * 16 + lg * 4 + l15) * 3;
            eab[off + 0] = o0 + bb0;
            eab[off + 1] = o1 + bb1;
            eab[off + 2] = o2 + bb2;
        }
    }
}

// ---------------- segment reduce: 16 lanes per node (R12 proven form) ------
__global__ __launch_bounds__(256) void reduce_kernel(
    const float* __restrict__ eab, const unsigned* __restrict__ start,
    const float* __restrict__ u, const int* __restrict__ batch,
    float* __restrict__ nred)
{
    int gid = blockIdx.x * 256 + threadIdx.x;
    int n = gid >> 4, sub = gid & 15;
    if (n >= NN) return;
    unsigned sbeg = start[n], send = start[n + 1];

    float s0 = 0.f, s1 = 0.f, s2 = 0.f;
    float m0 = -__builtin_inff(), m1 = -__builtin_inff(), m2 = -__builtin_inff();
    for (unsigned k = sbeg + sub; k < send; k += 16) {
        float v0 = eab[(size_t)k * 3 + 0];
        float v1 = eab[(size_t)k * 3 + 1];
        float v2 = eab[(size_t)k * 3 + 2];
        s0 += v0; s1 += v1; s2 += v2;
        m0 = fmaxf(m0, v0); m1 = fmaxf(m1, v1); m2 = fmaxf(m2, v2);
    }
    #pragma unroll
    for (int msk = 1; msk < 16; msk <<= 1) {
        s0 += __shfl_xor(s0, msk, 16);
        s1 += __shfl_xor(s1, msk, 16);
        s2 += __shfl_xor(s2, msk, 16);
        m0 = fmaxf(m0, __shfl_xor(m0, msk, 16));
        m1 = fmaxf(m1, __shfl_xor(m1, msk, 16));
        m2 = fmaxf(m2, __shfl_xor(m2, msk, 16));
    }
    if (sub == 0) {
        float deg = (float)(send - sbeg);
        if (send == sbeg) { m0 = 0.f; m1 = 0.f; m2 = 0.f; }
        float inv = 1.f / fmaxf(deg, 1.f);
        int b = batch[n];
        float* o = nred + (size_t)n * 12;
        o[0] = s0; o[1] = s1; o[2] = s2;
        o[3] = m0; o[4] = m1; o[5] = m2;
        o[6] = s0 * inv; o[7] = s1 * inv; o[8] = s2 * inv;
        o[9] = u[b * 2 + 0]; o[10] = u[b * 2 + 1];
    }
}

// ---------------- node MLP: wave-per-node, weight-stationary (R12) ---------
#define NMLP_BLOCKS 1024
#define NMLP_WAVES (NMLP_BLOCKS * 4)
__global__ __launch_bounds__(256, 4) void nodemlp_kernel(
    const float* x_in, const float* __restrict__ nred,
    const float* __restrict__ wt, const float* __restrict__ b2,
    float* x_out)
{
    int lane = threadIdx.x & 63;
    int wid = (blockIdx.x * 256 + threadIdx.x) >> 6;

    const float* ra = wt + lane * 28;
    const float* rb = wt + (lane + 64) * 28;
    float a0 = ra[0], a1 = ra[1], a2 = ra[2], a3 = ra[3], a4 = ra[4], a5 = ra[5],
          a6 = ra[6], a7 = ra[7], a8 = ra[8], a9 = ra[9], a10 = ra[10], a11 = ra[11],
          a12 = ra[12], a13 = ra[13], a14 = ra[14], a15 = ra[15], a16 = ra[16], a17 = ra[17],
          ab = ra[18], p0 = ra[19], p1 = ra[20], p2 = ra[21], p3 = ra[22], p4 = ra[23],
          p5 = ra[24], p6 = ra[25];
    float b0 = rb[0], b1 = rb[1], b2_ = rb[2], b3 = rb[3], b4 = rb[4], b5 = rb[5],
          b6 = rb[6], b7 = rb[7], b8 = rb[8], b9 = rb[9], b10 = rb[10], b11 = rb[11],
          b12 = rb[12], b13 = rb[13], b14 = rb[14], b15 = rb[15], b16 = rb[16], b17 = rb[17],
          bb = rb[18], q0 = rb[19], q1 = rb[20], q2 = rb[21], q3 = rb[22], q4 = rb[23],
          q5 = rb[24], q6 = rb[25];

    asm volatile("" : "+v"(a0), "+v"(a1), "+v"(a2), "+v"(a3), "+v"(a4), "+v"(a5),
                      "+v"(a6), "+v"(a7), "+v"(a8), "+v"(a9), "+v"(a10), "+v"(a11),
                      "+v"(a12), "+v"(a13), "+v"(a14), "+v"(a15), "+v"(a16), "+v"(a17),
                      "+v"(ab), "+v"(p0), "+v"(p1), "+v"(p2), "+v"(p3), "+v"(p4),
                      "+v"(p5), "+v"(p6));
    asm volatile("" : "+v"(b0), "+v"(b1), "+v"(b2_), "+v"(b3), "+v"(b4), "+v"(b5),
                      "+v"(b6), "+v"(b7), "+v"(b8), "+v"(b9), "+v"(b10), "+v"(b11),
                      "+v"(b12), "+v"(b13), "+v"(b14), "+v"(b15), "+v"(b16), "+v"(b17),
                      "+v"(bb), "+v"(q0), "+v"(q1), "+v"(q2), "+v"(q3), "+v"(q4),
                      "+v"(q5), "+v"(q6));

    float B0 = b2[0], B1 = b2[1], B2 = b2[2], B3 = b2[3], B4 = b2[4], B5 = b2[5], B6 = b2[6];

    const int nper = (NN + NMLP_WAVES - 1) / NMLP_WAVES;   // 25
    int n0 = wid * nper;
    int n1 = n0 + nper; if (n1 > NN) n1 = NN;

    #pragma unroll 2
    for (int n = n0; n < n1; ++n) {
        int nu = __builtin_amdgcn_readfirstlane(n);
        const float* xp = x_in + (size_t)nu * 7;
        const float* rp = nred + (size_t)nu * 12;
        float i0 = xp[0], i1 = xp[1], i2 = xp[2], i3 = xp[3], i4 = xp[4], i5 = xp[5], i6 = xp[6];
        float s0 = rp[0], s1 = rp[1], s2 = rp[2];
        float m0 = rp[3], m1 = rp[4], m2 = rp[5];
        float e0 = rp[6], e1 = rp[7], e2 = rp[8];
        float u0 = rp[9], u1 = rp[10];

        float ha = ab, hb = bb;
        ha += i0 * a0;  hb += i0 * b0;
        ha += i1 * a1;  hb += i1 * b1;
        ha += i2 * a2;  hb += i2 * b2_;
        ha += i3 * a3;  hb += i3 * b3;
        ha += i4 * a4;  hb += i4 * b4;
        ha += i5 * a5;  hb += i5 * b5;
        ha += i6 * a6;  hb += i6 * b6;
        ha += s0 * a7;  hb += s0 * b7;
        ha += s1 * a8;  hb += s1 * b8;
        ha += s2 * a9;  hb += s2 * b9;
        ha += m0 * a10; hb += m0 * b10;
        ha += m1 * a11; hb += m1 * b11;
        ha += m2 * a12; hb += m2 * b12;
        ha += e0 * a13; hb += e0 * b13;
        ha += e1 * a14; hb += e1 * b14;
        ha += e2 * a15; hb += e2 * b15;
        ha += u0 * a16; hb += u0 * b16;
        ha += u1 * a17; hb += u1 * b17;
        ha = fmaxf(ha, 0.f); hb = fmaxf(hb, 0.f);

        float c0 = ha * p0 + hb * q0;
        float c1 = ha * p1 + hb * q1;
        float c2 = ha * p2 + hb * q2;
        float c3 = ha * p3 + hb * q3;
        float c4 = ha * p4 + hb * q4;
        float c5 = ha * p5 + hb * q5;
        float c6 = ha * p6 + hb * q6;
        #pragma unroll
        for (int msk = 1; msk < 64; msk <<= 1) {
            c0 += __shfl_xor(c0, msk);
            c1 += __shfl_xor(c1, msk);
            c2 += __shfl_xor(c2, msk);
            c3 += __shfl_xor(c3, msk);
            c4 += __shfl_xor(c4, msk);
            c5 += __shfl_xor(c5, msk);
            c6 += __shfl_xor(c6, msk);
        }
        float o = c0 + B0;
        if (lane == 1) o = c1 + B1;
        if (lane == 2) o = c2 + B2;
        if (lane == 3) o = c3 + B3;
        if (lane == 4) o = c4 + B4;
        if (lane == 5) o = c5 + B5;
        if (lane == 6) o = c6 + B6;
        if (lane < 7) x_out[(size_t)nu * 7 + lane] = o;
    }
}

// ---------------- fused graph pool + output head (block per graph) ----------
__global__ __launch_bounds__(256) void pool_head_kernel(
    const float* __restrict__ x, const int* __restrict__ gstart,
    const float* __restrict__ u,
    const float* __restrict__ oW1, const float* __restrict__ ob1,
    const float* __restrict__ oW2, const float* __restrict__ ob2,
    const float* __restrict__ oW3, const float* __restrict__ ob3,
    const float* __restrict__ oW4, const float* __restrict__ ob4,
    float* __restrict__ out)
{
    int g = blockIdx.x, tid = threadIdx.x;
    int lane = tid & 63, wv = tid >> 6;
    int gs = gstart[g], ge = gstart[g + 1];

    float s0 = 0.f, s1 = 0.f, s2 = 0.f, s3 = 0.f, s4 = 0.f, s5 = 0.f, s6 = 0.f;
    float m0 = -__builtin_inff(), m1 = m0, m2 = m0, m3 = m0, m4 = m0, m5 = m0, m6 = m0;
    for (int n = gs + tid; n < ge; n += 256) {
        const float* xp = x + (size_t)n * 7;
        float v0 = xp[0], v1 = xp[1], v2 = xp[2], v3 = xp[3], v4 = xp[4], v5 = xp[5], v6 = xp[6];
        s0 += v0; s1 += v1; s2 += v2; s3 += v3; s4 += v4; s5 += v5; s6 += v6;
        m0 = fmaxf(m0, v0); m1 = fmaxf(m1, v1); m2 = fmaxf(m2, v2); m3 = fmaxf(m3, v3);
        m4 = fmaxf(m4, v4); m5 = fmaxf(m5, v5); m6 = fmaxf(m6, v6);
    }
    #pragma unroll
    for (int msk = 1; msk < 64; msk <<= 1) {
        s0 += __shfl_xor(s0, msk); s1 += __shfl_xor(s1, msk); s2 += __shfl_xor(s2, msk);
        s3 += __shfl_xor(s3, msk); s4 += __shfl_xor(s4, msk); s5 += __shfl_xor(s5, msk);
        s6 += __shfl_xor(s6, msk);
        m0 = fmaxf(m0, __shfl_xor(m0, msk)); m1 = fmaxf(m1, __shfl_xor(m1, msk));
        m2 = fmaxf(m2, __shfl_xor(m2, msk)); m3 = fmaxf(m3, __shfl_xor(m3, msk));
        m4 = fmaxf(m4, __shfl_xor(m4, msk)); m5 = fmaxf(m5, __shfl_xor(m5, msk));
        m6 = fmaxf(m6, __shfl_xor(m6, msk));
    }
    __shared__ float red[4][14];
    __shared__ float hin[23];
    __shared__ float ha[128];
    __shared__ float hbuf[128];
    if (lane == 0) {
        red[wv][0] = s0; red[wv][1] = s1; red[wv][2] = s2; red[wv][3] = s3;
        red[wv][4] = s4; red[wv][5] = s5; red[wv][6] = s6;
        red[wv][7] = m0; red[wv][8] = m1; red[wv][9] = m2; red[wv][10] = m3;
        red[wv][11] = m4; red[wv][12] = m5; red[wv][13] = m6;
    }
    __syncthreads();
    if (tid < 7) {
        float S = red[0][tid] + red[1][tid] + red[2][tid] + red[3][tid];
        float M = fmaxf(fmaxf(red[0][7 + tid], red[1][7 + tid]),
                        fmaxf(red[2][7 + tid], red[3][7 + tid]));
        float cntf = (float)(ge - gs);
        if (ge == gs) M = 0.f;
        hin[tid] = S;
        hin[7 + tid] = S / fmaxf(cntf, 1.f);
        hin[14 + tid] = M;
    }
    if (tid < 2) hin[21 + tid] = u[g * 2 + tid];
    __syncthreads();

    float h = 0.f;
    if (tid < 128) {
        h = ob1[tid];
        for (int i = 0; i < 23; ++i) h += hin[i] * oW1[i * 128 + tid];
        ha[tid] = fmaxf(h, 0.f);
    }
    __syncthreads();
    if (tid < 128) {
        h = ob2[tid];
        for (int i = 0; i < 128; ++i) h += ha[i] * oW2[i * 128 + tid];
        hbuf[tid] = fmaxf(h, 0.f);
    }
    __syncthreads();
    if (tid < 128) {
        h = ob3[tid];
        for (int i = 0; i < 128; ++i) h += hbuf[i] * oW3[i * 128 + tid];
        ha[tid] = fmaxf(h, 0.f) * oW4[tid];
    }
    __syncthreads();
    if (tid == 0) {
        float acc = ob4[0];
        for (int i = 0; i < 128; ++i) acc += ha[i];
        out[g] = acc;
    }
}

extern "C" void kernel_launch(void* const* d_in, const int* in_sizes, int n_in,
                              void* d_out, int out_size, void* d_ws, size_t ws_size,
                              hipStream_t stream) {
    const float* x         = (const float*)d_in[0];
    const float* edge_attr = (const float*)d_in[1];
    const float* u         = (const float*)d_in[2];
    const float* eW1 = (const float*)d_in[3];
    const float* eb1 = (const float*)d_in[4];
    const float* eW2 = (const float*)d_in[5];
    const float* eb2 = (const float*)d_in[6];
    const float* nW1 = (const float*)d_in[7];
    const float* nb1 = (const float*)d_in[8];
    const float* nW2 = (const float*)d_in[9];
    const float* nb2 = (const float*)d_in[10];
    const float* oW1 = (const float*)d_in[11];
    const float* ob1 = (const float*)d_in[12];
    const float* oW2 = (const float*)d_in[13];
    const float* ob2 = (const float*)d_in[14];
    const float* oW3 = (const float*)d_in[15];
    const float* ob3 = (const float*)d_in[16];
    const float* oW4 = (const float*)d_in[17];
    const float* ob4 = (const float*)d_in[18];
    const int* edge_index = (const int*)d_in[19];
    const int* batch      = (const int*)d_in[20];
    const int* row = edge_index;
    const int* col = edge_index + NE;

    // workspace layout
    float* ws        = (float*)d_ws;
    float* eab       = ws;                                   // E*3     19.2 MB
    float* eabT      = eab + (size_t)NE * 3;                 // E*3     19.2 MB
    float* ws_x      = eabT + (size_t)NE * 3;                // N*7      2.8 MB
    int2*  rc        = (int2*)(ws_x + (size_t)NN * 7);       // E       12.8 MB
    int2*  rcT       = rc + (size_t)NE;                      // E       12.8 MB
    float* nred      = (float*)(rcT + (size_t)NE);           // N*12     4.8 MB
    unsigned* ghist  = (unsigned*)(nred + (size_t)NN * 12);  // NBH*NBINS  4 MB
    unsigned* goff   = ghist + (size_t)NBH * NBINS;          // NBH*NBINS  4 MB
    unsigned* total  = goff + (size_t)NBH * NBINS;           // NBINS
    unsigned* binbase = total + NBINS;                       // NBINS+1 (+pad)
    unsigned* startv = binbase + NBINS + 4;                  // N+1
    int* gstart      = (int*)(startv + NN + 4);              // 257 (+pad)
    float* nwt       = (float*)(gstart + 260);               // 2*128*28
    float* w2f       = nwt + 2 * 128 * 28;                   // 2*1536
    float* b1f       = w2f + 2 * 1536;                       // 2*512
    uintptr_t ewb    = ((uintptr_t)(b1f + 2 * 512) + 15) & ~(uintptr_t)15;
    short* ewf       = (short*)ewb;                          // 2*4096 shorts

    dim3 b256(256);
    dim3 gn(NB);                        // 391

    // ---- atomic-free two-level partition -> node-sorted CSR ----
    hist_kernel<<<NBH, b256, 0, stream>>>(col, ghist);
    gbound_kernel<<<gn, b256, 0, stream>>>(batch, gstart);
    scanB_kernel<<<NBINS, 1024, 0, stream>>>(ghist, goff, total);
    scanC_kernel<<<1, 1024, 0, stream>>>(total, binbase);
    scatterD_kernel<<<NBH, b256, 0, stream>>>(row, col, edge_attr, goff, binbase, rcT, eabT);
    bucketsort_kernel<<<NBUCK, b256, 0, stream>>>(rcT, eabT, binbase, rc, eab, startv);

    // weight prep
    {
        int t = 2 * 4096 + 2 * 1536 + 2 * 512 + 2 * 128 * 28;  // 19456
        prep_kernel<<<(t + 255) / 256, b256, 0, stream>>>(
            eW1, eb1, eW2, nW1, nb1, nW2, ewf, w2f, b1f, nwt);
    }

    dim3 gemf(2048);                  // edge MFMA grid (8192 waves)
    dim3 gr((NN * 16 + 255) / 256);   // 6250 blocks for reduce

    // ---- layer 0 ----
    edge_kernel<<<gemf, b256, 0, stream>>>(x, eab, rc, ewf, w2f, b1f, eb2);
    reduce_kernel<<<gr, b256, 0, stream>>>(eab, startv, u, batch, nred);
    nodemlp_kernel<<<NMLP_BLOCKS, b256, 0, stream>>>(x, nred, nwt, nb2, ws_x);

    // ---- layer 1 ----
    edge_kernel<<<gemf, b256, 0, stream>>>(ws_x, eab, rc,
        ewf + 4096, w2f + 1536, b1f + 512, eb2 + 3);
    reduce_kernel<<<gr, b256, 0, stream>>>(eab, startv, u, batch, nred);
    nodemlp_kernel<<<NMLP_BLOCKS, b256, 0, stream>>>(ws_x, nred, nwt + 128 * 28, nb2 + 7, ws_x);

    // ---- fused pool + head ----
    pool_head_kernel<<<NG, b256, 0, stream>>>(ws_x, gstart, u,
        oW1, ob1, oW2, ob2, oW3, ob3, oW4, ob4, (float*)d_out);
}